// Round 8
// baseline (167.736 us; speedup 1.0000x reference)
//
#include <hip/hip_runtime.h>
#include <hip/hip_cooperative_groups.h>

namespace cg = cooperative_groups;

// ---------------------------------------------------------------------------
// LearnedBoardEncoder, factorized, single cooperative kernel (+ fallback).
//
// Token space is tiny: LN(W[c]@piece[p] + b[c] + square[s]) has 7*3*64=1344
// distinct rows; special tokens 2+16+9=27. Phase 1 (22 blocks): build the
// 1371-row LN'd table in workspace. grid.sync(). Phase 2 (all blocks):
// grid-stride gather, one wave per output row, nontemporal f32x4 stores
// (R6 evidence: NT stores −5.4 us; keeps table L2-resident).
//
// R8: R7 failed because the cooperative launch silently errored (2048 blocks
// = exact co-residency ceiling). Now: 512 blocks (2/CU, guaranteed), no
// min-waves launch_bounds, and a checked return code with fallback to the
// proven R6 three-kernel path.
// ---------------------------------------------------------------------------

#define DIM 256
#define NPT 7
#define NCOL 3
#define NROWS_SQ (NPT * NCOL * 64)   // 1344
#define ROW_TURN 1344                // 2 rows
#define ROW_CASTLE 1346              // 16 rows
#define ROW_EP 1362                  // 9 rows
#define NROWS_TOT 1371
#define EPSV 1e-5f
#define COOP_GRID 512

typedef float f32x4 __attribute__((ext_vector_type(4)));

__device__ __forceinline__ float4 ln4(float4 x, float4 g, float4 bb) {
    float s = x.x + x.y + x.z + x.w;
    #pragma unroll
    for (int m = 1; m < 64; m <<= 1) s += __shfl_xor(s, m, 64);
    float mu = s * (1.0f / DIM);
    float dx = x.x - mu, dy = x.y - mu, dz = x.z - mu, dw = x.w - mu;
    float v = dx * dx + dy * dy + dz * dz + dw * dw;
    #pragma unroll
    for (int m = 1; m < 64; m <<= 1) v += __shfl_xor(v, m, 64);
    float inv = rsqrtf(v * (1.0f / DIM) + EPSV);
    return make_float4(dx * inv * g.x + bb.x,
                       dy * inv * g.y + bb.y,
                       dz * inv * g.z + bb.z,
                       dw * inv * g.w + bb.w);
}

__device__ __forceinline__ void build_table_block(
        int e, int tid, int wave, int lane,
        const float* __restrict__ piece_table,
        const float* __restrict__ W,
        const float* __restrict__ bvec,
        const float* __restrict__ square_table,
        const float* __restrict__ turn_table,
        const float* __restrict__ castling_table,
        const float* __restrict__ ep_table,
        const float* __restrict__ gamma,
        const float* __restrict__ beta,
        float* __restrict__ table) {
    if (e < NPT * NCOL) {
        int p = e / NCOL, c = e % NCOL;
        __shared__ float pt[DIM];
        __shared__ float projs[DIM];
        pt[tid] = piece_table[p * DIM + tid];
        __syncthreads();
        const float4* w4 = (const float4*)(W + (size_t)c * DIM * DIM + (size_t)tid * DIM);
        float acc = bvec[c * DIM + tid];
        #pragma unroll 8
        for (int k = 0; k < DIM / 4; ++k) {
            float4 w = w4[k];
            acc += w.x * pt[k * 4 + 0] + w.y * pt[k * 4 + 1]
                 + w.z * pt[k * 4 + 2] + w.w * pt[k * 4 + 3];
        }
        projs[tid] = acc;
        __syncthreads();

        float4 g  = ((const float4*)gamma)[lane];
        float4 bb = ((const float4*)beta)[lane];
        float4 a = ((const float4*)projs)[lane];
        float* tbase = table + (size_t)(p * (NCOL * 64) + c * 64) * DIM;
        for (int s = wave; s < 64; s += 4) {
            float4 q = ((const float4*)(square_table + s * DIM))[lane];
            float4 x = make_float4(a.x + q.x, a.y + q.y, a.z + q.z, a.w + q.w);
            ((float4*)(tbase + (size_t)s * DIM))[lane] = ln4(x, g, bb);
        }
    } else if (e == NPT * NCOL) {
        float4 g  = ((const float4*)gamma)[lane];
        float4 bb = ((const float4*)beta)[lane];
        for (int w = wave; w < 27; w += 4) {
            float4 x;
            if (w < 2) {
                x = ((const float4*)(turn_table + w * DIM))[lane];
            } else if (w < 18) {
                x = ((const float4*)(castling_table + (w - 2) * DIM))[lane];
            } else {
                x = ((const float4*)(ep_table + (w - 18) * DIM))[lane];
            }
            ((float4*)(table + (size_t)(ROW_TURN + w) * DIM))[lane] = ln4(x, g, bb);
        }
    }
}

__device__ __forceinline__ int row_of(
        int r, const int* __restrict__ piece_ids, const int* __restrict__ color_ids,
        const int* __restrict__ turn, const int* __restrict__ castling,
        const int* __restrict__ ep_file) {
    int b = r / 67;
    int t = r - b * 67;
    if (t == 0) return ROW_TURN + turn[b];
    if (t == 1) return ROW_CASTLE + castling[b];
    if (t == 2) return ROW_EP + ep_file[b];
    int s = t - 3;
    int idx = b * 64 + s;
    return piece_ids[idx] * (NCOL * 64) + color_ids[idx] * 64 + s;
}

// ---- Fused cooperative kernel ----
__global__ __launch_bounds__(256) void fused_kernel(
        const int* __restrict__ piece_ids,
        const int* __restrict__ color_ids,
        const int* __restrict__ turn,
        const int* __restrict__ castling,
        const int* __restrict__ ep_file,
        const float* __restrict__ piece_table,
        const float* __restrict__ W,
        const float* __restrict__ bvec,
        const float* __restrict__ square_table,
        const float* __restrict__ turn_table,
        const float* __restrict__ castling_table,
        const float* __restrict__ ep_table,
        const float* __restrict__ gamma,
        const float* __restrict__ beta,
        float* __restrict__ table,
        float* __restrict__ out,
        int nrows) {
    int e = blockIdx.x;
    int tid = threadIdx.x;
    int wave = tid >> 6, lane = tid & 63;

    build_table_block(e, tid, wave, lane, piece_table, W, bvec, square_table,
                      turn_table, castling_table, ep_table, gamma, beta, table);

    cg::this_grid().sync();

    int stride = gridDim.x * 4;
    for (int r = e * 4 + wave; r < nrows; r += stride) {
        int row = row_of(r, piece_ids, color_ids, turn, castling, ep_file);
        f32x4 v = ((const f32x4*)(table + (size_t)row * DIM))[lane];
        __builtin_nontemporal_store(v, (f32x4*)(out + (size_t)r * DIM) + lane);
    }
}

// ---- Fallback path: proven R6 kernels ----
__global__ __launch_bounds__(256) void table_kernel(
        const float* __restrict__ piece_table,
        const float* __restrict__ W,
        const float* __restrict__ bvec,
        const float* __restrict__ square_table,
        const float* __restrict__ turn_table,
        const float* __restrict__ castling_table,
        const float* __restrict__ ep_table,
        const float* __restrict__ gamma,
        const float* __restrict__ beta,
        float* __restrict__ table) {
    build_table_block(blockIdx.x, threadIdx.x, threadIdx.x >> 6, threadIdx.x & 63,
                      piece_table, W, bvec, square_table, turn_table,
                      castling_table, ep_table, gamma, beta, table);
}

__global__ void gather_kernel(const int* __restrict__ piece_ids,
                              const int* __restrict__ color_ids,
                              const int* __restrict__ turn,
                              const int* __restrict__ castling,
                              const int* __restrict__ ep_file,
                              const float* __restrict__ table,
                              float* __restrict__ out,
                              int nrows) {
    int r = blockIdx.x * 4 + (threadIdx.x >> 6);
    if (r >= nrows) return;
    int lane = threadIdx.x & 63;
    int row = row_of(r, piece_ids, color_ids, turn, castling, ep_file);
    f32x4 v = ((const f32x4*)(table + (size_t)row * DIM))[lane];
    __builtin_nontemporal_store(v, (f32x4*)(out + (size_t)r * DIM) + lane);
}

extern "C" void kernel_launch(void* const* d_in, const int* in_sizes, int n_in,
                              void* d_out, int out_size, void* d_ws, size_t ws_size,
                              hipStream_t stream) {
    const int*   piece_ids      = (const int*)d_in[0];
    const int*   color_ids      = (const int*)d_in[1];
    const int*   turn           = (const int*)d_in[2];
    const int*   castling       = (const int*)d_in[3];
    const int*   ep_file        = (const int*)d_in[4];
    const float* piece_table    = (const float*)d_in[5];
    const float* W              = (const float*)d_in[6];
    const float* bvec           = (const float*)d_in[7];
    const float* square_table   = (const float*)d_in[8];
    const float* turn_table     = (const float*)d_in[9];
    const float* castling_table = (const float*)d_in[10];
    const float* ep_table       = (const float*)d_in[11];
    const float* gamma          = (const float*)d_in[12];
    const float* beta           = (const float*)d_in[13];
    float* out = (float*)d_out;

    int B = in_sizes[0] / 64;
    int nrows = B * 67;
    float* table = (float*)d_ws;                 // 1371 * 256 floats

    void* args[] = {
        (void*)&piece_ids, (void*)&color_ids, (void*)&turn, (void*)&castling,
        (void*)&ep_file, (void*)&piece_table, (void*)&W, (void*)&bvec,
        (void*)&square_table, (void*)&turn_table, (void*)&castling_table,
        (void*)&ep_table, (void*)&gamma, (void*)&beta,
        (void*)&table, (void*)&out, (void*)&nrows,
    };
    hipError_t err = hipLaunchCooperativeKernel((const void*)fused_kernel,
                                                dim3(COOP_GRID), dim3(256),
                                                args, 0, stream);
    if (err != hipSuccess) {
        // Fallback: proven R6 three-kernel path.
        table_kernel<<<NPT * NCOL + 1, 256, 0, stream>>>(
            piece_table, W, bvec, square_table, turn_table, castling_table,
            ep_table, gamma, beta, table);
        gather_kernel<<<(nrows + 3) / 4, 256, 0, stream>>>(
            piece_ids, color_ids, turn, castling, ep_file, table, out, nrows);
    }
}